// Round 1
// baseline (11202.635 us; speedup 1.0000x reference)
//
#include <hip/hip_runtime.h>

// ModernNCA fused pipeline, round 1: correctness-first fp32 vector compute,
// bf16 storage for encodings (MFMA-ready layout for round 2).
//
// K_enc  : PLR + encoder GEMM (used for both candidates[100000] and queries[1024])
//          writes ce/xe rows as bf16 + fp32 squared norms.
// K_dist : fused distance + exp + per-class binning (no 1024x100000 matrix).
// K_fin  : out[q][c] = log(bins[q][c]/Z[q] + 1e-7).

#define TWO_PI 6.283185307179586f
#define N_CAND 100000
#define N_Q    1024

typedef unsigned short ushort_t;
typedef unsigned int uint_t;

__device__ __forceinline__ float bf2f(ushort_t h) {
    union { uint_t u; float f; } c; c.u = ((uint_t)h) << 16; return c.f;
}
__device__ __forceinline__ float bfu_lo(uint_t u) {
    union { uint_t i; float f; } c; c.i = u << 16; return c.f;
}
__device__ __forceinline__ float bfu_hi(uint_t u) {
    union { uint_t i; float f; } c; c.i = u & 0xffff0000u; return c.f;
}
__device__ __forceinline__ ushort_t f2bf(float f) {
    union { float f; uint_t u; } c; c.f = f;
    uint_t u = c.u + 0x7fffu + ((c.u >> 16) & 1u);   // RNE; inputs finite
    return (ushort_t)(u >> 16);
}

// ---------------------------------------------------------------------------
// Encoder: 32 rows per block. Phase A: PLR -> feat (bf16 in LDS).
// Phase B: feat(32x776) @ enc_w^T -> 32x512, register tile 4c x 16e per thread.
// ---------------------------------------------------------------------------
__global__ __launch_bounds__(256) void encode_kernel(
    const float* __restrict__ vin,    // [nrows][32]
    const float* __restrict__ freq,   // [24][16]
    const float* __restrict__ plrw,   // [32][32]
    const float* __restrict__ plrb,   // [32]
    const float* __restrict__ encw,   // [512][776]
    const float* __restrict__ encb,   // [512]
    ushort_t*    __restrict__ enc_out,// [nrows][512] bf16
    float*       __restrict__ sq_out) // [nrows]
{
    __shared__ float    s_cx[32 * 32];      //  4096 B
    __shared__ float    s_pw[32 * 32];      //  4096 B
    __shared__ float    s_pb[32];           //   128 B
    __shared__ float    s_csq[32];          //   128 B
    __shared__ ushort_t s_feat[32 * 776];   // 49664 B
    __shared__ ushort_t s_z[4 * 24 * 32];   //  6144 B   (total 64256 B)

    const int t = threadIdx.x;
    const long base = (long)blockIdx.x * 32;

    ((float4*)s_cx)[t & 255] = ((const float4*)(vin + base * 32))[t];
    ((float4*)s_pw)[t] = ((const float4*)plrw)[t];
    if (t < 8)  ((float4*)s_pb)[t] = ((const float4*)plrb)[t];
    if (t < 32) s_csq[t] = 0.f;
    __syncthreads();

    // ---- Phase A: PLR, 4 candidates per sub-batch ----
    for (int sub = 0; sub < 8; ++sub) {
        if (sub) __syncthreads();           // protect s_z reuse
        #pragma unroll
        for (int i = 0; i < 6; ++i) {       // 1536 sincos pairs
            int p = t + 256 * i;
            int ci = p / 384;
            int rem = p - ci * 384;
            int n = rem >> 4, f = rem & 15;
            float v = s_cx[(sub * 4 + ci) * 32 + n];
            float a = TWO_PI * freq[n * 16 + f] * v;
            float sv, cv;
            __sincosf(a, &sv, &cv);
            s_z[(ci * 24 + n) * 32 + f]      = f2bf(cv);
            s_z[(ci * 24 + n) * 32 + 16 + f] = f2bf(sv);
        }
        __syncthreads();
        #pragma unroll
        for (int i = 0; i < 12; ++i) {      // 3072 feat outputs
            int o = t + 256 * i;
            int ci = o / 768;
            int rem = o - ci * 768;
            int n = rem >> 5, e = rem & 31;
            float s = s_pb[e];
            const ushort_t* zp = &s_z[(ci * 24 + n) * 32];
            #pragma unroll
            for (int f = 0; f < 32; ++f) s += bf2f(zp[f]) * s_pw[e * 32 + f];
            s_feat[(sub * 4 + ci) * 776 + (n << 5) + e] = f2bf(fmaxf(s, 0.f));
        }
    }
    { // v_cat passthrough: feat[c][768+j] = v[c][24+j]
        int c = t >> 3, j = t & 7;
        s_feat[c * 776 + 768 + j] = f2bf(s_cx[c * 32 + 24 + j]);
    }
    __syncthreads();

    // ---- Phase B: 32x512 = feat(32x776) @ W^T, thread tile 4c x 16e ----
    const int eg = t & 31;        // e = eg + 32*ei
    const int cg = t >> 5;        // c = cg*4 + cc
    float acc[4][16];
    #pragma unroll
    for (int cc = 0; cc < 4; ++cc)
        #pragma unroll
        for (int ei = 0; ei < 16; ++ei) acc[cc][ei] = 0.f;

    for (int kc = 0; kc < 97; ++kc) {
        const int k0 = kc * 8;
        float ff[4][8];
        #pragma unroll
        for (int cc = 0; cc < 4; ++cc) {
            uint4 u = *(const uint4*)&s_feat[(cg * 4 + cc) * 776 + k0];
            ff[cc][0] = bfu_lo(u.x); ff[cc][1] = bfu_hi(u.x);
            ff[cc][2] = bfu_lo(u.y); ff[cc][3] = bfu_hi(u.y);
            ff[cc][4] = bfu_lo(u.z); ff[cc][5] = bfu_hi(u.z);
            ff[cc][6] = bfu_lo(u.w); ff[cc][7] = bfu_hi(u.w);
        }
        #pragma unroll
        for (int ei = 0; ei < 16; ++ei) {
            const float* wr = encw + (size_t)(eg + (ei << 5)) * 776 + k0;
            float4 w0 = *(const float4*)(wr);
            float4 w1 = *(const float4*)(wr + 4);
            #pragma unroll
            for (int cc = 0; cc < 4; ++cc) {
                acc[cc][ei] += ff[cc][0] * w0.x + ff[cc][1] * w0.y
                             + ff[cc][2] * w0.z + ff[cc][3] * w0.w
                             + ff[cc][4] * w1.x + ff[cc][5] * w1.y
                             + ff[cc][6] * w1.z + ff[cc][7] * w1.w;
            }
        }
    }

    // epilogue: +bias, bf16 store, squared norms
    #pragma unroll
    for (int cc = 0; cc < 4; ++cc) {
        int c = cg * 4 + cc;
        long row = base + c;
        float sq = 0.f;
        #pragma unroll
        for (int ei = 0; ei < 16; ++ei) {
            int e = eg + (ei << 5);
            float v = acc[cc][ei] + encb[e];
            sq += v * v;
            enc_out[row * 512 + e] = f2bf(v);
        }
        atomicAdd(&s_csq[c], sq);
    }
    __syncthreads();
    if (t < 32) sq_out[base + t] = s_csq[t];
}

// ---------------------------------------------------------------------------
// Distance + softmax binning. Block: 64 queries x 1024 candidates.
// Thread tile 4q x 4c (strided by 16), k in 4 chunks of 128.
// ---------------------------------------------------------------------------
__global__ __launch_bounds__(256) void dist_kernel(
    const ushort_t* __restrict__ xe,   // [1024][512] bf16
    const ushort_t* __restrict__ ce,   // [100000][512] bf16
    const float*    __restrict__ xsq,  // [1024]
    const float*    __restrict__ csq,  // [100000]
    const int*      __restrict__ cy,   // [100000]
    float*          __restrict__ gbins)// [1024][10]
{
    __shared__ ushort_t s_xe[64 * 132];   // 16896 B (pad 132 breaks conflicts)
    __shared__ float    s_ce[64 * 132];   // 33792 B
    __shared__ float    s_bins[64 * 10];  //  2560 B
    __shared__ float    s_xsq[64];
    __shared__ float    s_csq[64];
    __shared__ int      s_y[64];

    const int t = threadIdx.x;
    const int qbase = blockIdx.x * 64;
    const long cb = (long)blockIdx.y * 1024;

    for (int i = t; i < 640; i += 256) s_bins[i] = 0.f;
    if (t < 64) s_xsq[t] = xsq[qbase + t];

    const int cp = t & 15;    // c_l = cp + 16*ci
    const int qp = t >> 4;    // q_l = qp + 16*qi

    for (int cs = 0; cs < 16; ++cs) {
        __syncthreads();      // protect s_y/s_csq restage vs prev epilogue
        const long cbase = cb + cs * 64;
        if (t < 64) {
            long jc = cbase + t;
            bool ok = jc < N_CAND;
            s_y[t]   = ok ? cy[jc] : -1;
            s_csq[t] = ok ? csq[jc] : 0.f;
        }
        float acc[4][4] = {};

        for (int kc = 0; kc < 4; ++kc) {
            __syncthreads();  // prev inner-loop reads done before restage
            const int k0 = kc * 128;
            #pragma unroll
            for (int s = 0; s < 8; ++s) {   // stage xe 64x128 bf16
                int i = t + 256 * s;
                int q = i >> 5, j4 = i & 31;
                ushort4 u = *(const ushort4*)&xe[(long)(qbase + q) * 512 + k0 + j4 * 4];
                *(ushort4*)&s_xe[q * 132 + j4 * 4] = u;
            }
            #pragma unroll
            for (int s = 0; s < 8; ++s) {   // stage ce 64x128 -> f32
                int i = t + 256 * s;
                int c = i >> 5, j4 = i & 31;
                long jc = cbase + c;
                float4 v = {0.f, 0.f, 0.f, 0.f};
                if (jc < N_CAND) {
                    ushort4 u = *(const ushort4*)&ce[jc * 512 + k0 + j4 * 4];
                    v.x = bf2f(u.x); v.y = bf2f(u.y); v.z = bf2f(u.z); v.w = bf2f(u.w);
                }
                *(float4*)&s_ce[c * 132 + j4 * 4] = v;
            }
            __syncthreads();

            for (int k4 = 0; k4 < 32; ++k4) {
                float xq[4][4];
                #pragma unroll
                for (int qi = 0; qi < 4; ++qi) {
                    ushort4 u = *(const ushort4*)&s_xe[(qp + (qi << 4)) * 132 + k4 * 4];
                    xq[qi][0] = bf2f(u.x); xq[qi][1] = bf2f(u.y);
                    xq[qi][2] = bf2f(u.z); xq[qi][3] = bf2f(u.w);
                }
                #pragma unroll
                for (int ci = 0; ci < 4; ++ci) {
                    const float4 cv = *(const float4*)&s_ce[(cp + (ci << 4)) * 132 + k4 * 4];
                    #pragma unroll
                    for (int qi = 0; qi < 4; ++qi)
                        acc[qi][ci] += xq[qi][0] * cv.x + xq[qi][1] * cv.y
                                     + xq[qi][2] * cv.z + xq[qi][3] * cv.w;
                }
            }
        }

        // epilogue: d = sqrt(|x|^2 + |c|^2 - 2 dot), bin exp(-d) by class
        #pragma unroll
        for (int ci = 0; ci < 4; ++ci) {
            int c_l = cp + (ci << 4);
            int cls = s_y[c_l];
            if (cls < 0) continue;
            float cq = s_csq[c_l];
            #pragma unroll
            for (int qi = 0; qi < 4; ++qi) {
                int q_l = qp + (qi << 4);
                float sq = s_xsq[q_l] + cq - 2.f * acc[qi][ci];
                float d = sqrtf(fmaxf(sq, 1e-12f));
                float p = __expf(-d);
                atomicAdd(&s_bins[q_l * 10 + cls], p);
            }
        }
    }
    __syncthreads();
    for (int i = t; i < 640; i += 256)
        atomicAdd(&gbins[(long)(qbase + i / 10) * 10 + (i % 10)], s_bins[i]);
}

// ---------------------------------------------------------------------------
__global__ __launch_bounds__(256) void final_kernel(
    const float* __restrict__ gbins, float* __restrict__ out)
{
    int q = blockIdx.x * 256 + threadIdx.x;
    if (q >= N_Q) return;
    float b[10], Z = 0.f;
    #pragma unroll
    for (int c = 0; c < 10; ++c) { b[c] = gbins[q * 10 + c]; Z += b[c]; }
    float inv = 1.f / Z;
    #pragma unroll
    for (int c = 0; c < 10; ++c)
        out[q * 10 + c] = logf(b[c] * inv + 1e-7f);
}

// ---------------------------------------------------------------------------
extern "C" void kernel_launch(void* const* d_in, const int* in_sizes, int n_in,
                              void* d_out, int out_size, void* d_ws, size_t ws_size,
                              hipStream_t stream) {
    const float* x  = (const float*)d_in[0];
    const float* cx = (const float*)d_in[1];
    const int*   cy = (const int*)d_in[2];
    const float* fr = (const float*)d_in[3];
    const float* pw = (const float*)d_in[4];
    const float* pb = (const float*)d_in[5];
    const float* ew = (const float*)d_in[6];
    const float* eb = (const float*)d_in[7];
    float* out = (float*)d_out;

    char* ws = (char*)d_ws;
    ushort_t* ce   = (ushort_t*)(ws);                 // 102,400,000 B
    ushort_t* xe   = (ushort_t*)(ws + 102400000);     //   1,048,576 B
    float*    xsq  = (float*)   (ws + 103448576);     //       4,096 B
    float*    csq  = (float*)   (ws + 103452672);     //     400,000 B
    float*    gbin = (float*)   (ws + 103852672);     //      40,960 B  (total ~99.1 MiB)

    hipMemsetAsync(gbin, 0, N_Q * 10 * sizeof(float), stream);
    encode_kernel<<<N_CAND / 32, 256, 0, stream>>>(cx, fr, pw, pb, ew, eb, ce, csq);
    encode_kernel<<<N_Q / 32,    256, 0, stream>>>(x,  fr, pw, pb, ew, eb, xe, xsq);
    dist_kernel<<<dim3(16, 98), 256, 0, stream>>>(xe, ce, xsq, csq, cy, gbin);
    final_kernel<<<4, 256, 0, stream>>>(gbin, out);
}

// Round 2
// 2091.894 us; speedup vs baseline: 5.3553x; 5.3553x over previous
//
#include <hip/hip_runtime.h>

// ModernNCA fused pipeline, round 2: MFMA for both GEMMs.
// - wsplit_kernel : encw fp32 -> bf16 hi/lo pair, zero-padded K 776->800.
// - encode_kernel : PLR (VALU, conflict-free s_pwT) + MFMA encoder GEMM.
// - dist_kernel   : MFMA xe.ce^T + fused sqrt/exp/class-binning.
// - final_kernel  : log(bins/Z + eps).

#define TWO_PI 6.283185307179586f
#define N_CAND 100000
#define N_Q    1024

typedef unsigned short ushort_t;
typedef unsigned int uint_t;
typedef __attribute__((ext_vector_type(8))) short short8;   // 8 bf16 = 4 VGPRs
typedef __attribute__((ext_vector_type(4))) float f32x4;

__device__ __forceinline__ float bf2f(ushort_t h) {
    union { uint_t u; float f; } c; c.u = ((uint_t)h) << 16; return c.f;
}
__device__ __forceinline__ ushort_t f2bf(float f) {
    union { float f; uint_t u; } c; c.f = f;
    uint_t u = c.u + 0x7fffu + ((c.u >> 16) & 1u);   // RNE; inputs finite
    return (ushort_t)(u >> 16);
}

// ---------------------------------------------------------------------------
// Prepass: encw[512][776] fp32 -> w_hi/w_lo bf16 [512][800] (zero pad tail).
// ---------------------------------------------------------------------------
__global__ __launch_bounds__(256) void wsplit_kernel(
    const float* __restrict__ encw, ushort_t* __restrict__ w_hi,
    ushort_t* __restrict__ w_lo)
{
    int idx = blockIdx.x * 256 + threadIdx.x;     // 512*800 = 409600
    if (idx >= 512 * 800) return;
    int n = idx / 800, k = idx - n * 800;
    float w = (k < 776) ? encw[n * 776 + k] : 0.f;
    ushort_t h = f2bf(w);
    w_hi[idx] = h;
    w_lo[idx] = f2bf(w - bf2f(h));
}

// ---------------------------------------------------------------------------
// Encoder: 32 rows/block. Phase A: PLR -> s_feat bf16 [32][808].
// Phase B: MFMA 16x16x32 bf16, feat @ (w_hi + w_lo)^T, 4 waves x 128 cols.
// ---------------------------------------------------------------------------
__global__ __launch_bounds__(256) void encode_kernel(
    const float* __restrict__ vin,    // [nrows][32]
    const float* __restrict__ freq,   // [24][16]
    const float* __restrict__ plrw,   // [32][32]
    const float* __restrict__ plrb,   // [32]
    const ushort_t* __restrict__ w_hi,// [512][800] bf16
    const ushort_t* __restrict__ w_lo,// [512][800] bf16
    const float* __restrict__ encb,   // [512]
    ushort_t*    __restrict__ enc_out,// [nrows][512] bf16
    float*       __restrict__ sq_out) // [nrows]
{
    __shared__ float    s_cx[32 * 32];            //  4096 B
    __shared__ float    s_pwT[32 * 32];           //  4096 B (transposed: [f][e])
    __shared__ float    s_pb[32];
    __shared__ float    s_csq[32];
    __shared__ __align__(16) ushort_t s_feat[32 * 808];  // 51712 B (pad->2-way only)
    __shared__ __align__(16) ushort_t s_z[4 * 24 * 32];  //  6144 B

    const int t = threadIdx.x;
    const long base = (long)blockIdx.x * 32;

    ((float4*)s_cx)[t] = ((const float4*)(vin + base * 32))[t];
    {   // transpose plr_w into LDS: s_pwT[f][e] -> bank = e = lane, conflict-free
        float4 v = ((const float4*)plrw)[t];
        int e = t >> 3, f0 = (t & 7) * 4;
        s_pwT[(f0 + 0) * 32 + e] = v.x;
        s_pwT[(f0 + 1) * 32 + e] = v.y;
        s_pwT[(f0 + 2) * 32 + e] = v.z;
        s_pwT[(f0 + 3) * 32 + e] = v.w;
    }
    if (t < 8)  ((float4*)s_pb)[t] = ((const float4*)plrb)[t];
    if (t < 32) s_csq[t] = 0.f;
    {   // zero-pad feat K-tail [776,808)
        int row = t >> 3, kk = 776 + (t & 7) * 4;
        ushort_t* p = &s_feat[row * 808 + kk];
        p[0] = 0; p[1] = 0; p[2] = 0; p[3] = 0;
    }
    __syncthreads();

    // ---- Phase A: PLR, 4 rows per sub-batch ----
    for (int sub = 0; sub < 8; ++sub) {
        if (sub) __syncthreads();           // protect s_z reuse
        #pragma unroll
        for (int i = 0; i < 6; ++i) {       // 1536 sincos pairs
            int p = t + 256 * i;
            int ci = p / 384;
            int rem = p - ci * 384;
            int n = rem >> 4, f = rem & 15;
            float v = s_cx[(sub * 4 + ci) * 32 + n];
            float a = TWO_PI * freq[n * 16 + f] * v;
            float sv, cv;
            __sincosf(a, &sv, &cv);
            s_z[(ci * 24 + n) * 32 + f]      = f2bf(cv);
            s_z[(ci * 24 + n) * 32 + 16 + f] = f2bf(sv);
        }
        __syncthreads();
        #pragma unroll
        for (int i = 0; i < 12; ++i) {      // 3072 feat outputs
            int o = t + 256 * i;
            int ci = o / 768;
            int rem = o - ci * 768;
            int n = rem >> 5, e = rem & 31;
            float s = s_pb[e];
            const ushort_t* zp = &s_z[(ci * 24 + n) * 32];
            #pragma unroll
            for (int f = 0; f < 32; ++f) s += bf2f(zp[f]) * s_pwT[f * 32 + e];
            s_feat[(sub * 4 + ci) * 808 + (n << 5) + e] = f2bf(fmaxf(s, 0.f));
        }
    }
    { // v_cat passthrough
        int c = t >> 3, j = t & 7;
        s_feat[c * 808 + 768 + j] = f2bf(s_cx[c * 32 + 24 + j]);
    }
    __syncthreads();

    // ---- Phase B: MFMA. wave w covers e in [w*128, w*128+128) ----
    const int lane = t & 63, w = t >> 6;
    const int lr = lane & 15;             // row/col within 16-tile
    const int lk = (lane >> 4) * 8;       // k-offset within 32-chunk

    f32x4 zero4 = {0.f, 0.f, 0.f, 0.f};
    f32x4 acc[2][8];
    #pragma unroll
    for (int mt = 0; mt < 2; ++mt)
        #pragma unroll
        for (int nt = 0; nt < 8; ++nt) acc[mt][nt] = zero4;

    for (int kc = 0; kc < 25; ++kc) {
        const int k0 = kc * 32;
        short8 a0 = *(const short8*)&s_feat[lr * 808 + k0 + lk];
        short8 a1 = *(const short8*)&s_feat[(16 + lr) * 808 + k0 + lk];
        #pragma unroll
        for (int nt = 0; nt < 8; ++nt) {
            const size_t n = (size_t)(w * 128 + nt * 16 + lr);
            short8 bh = *(const short8*)&w_hi[n * 800 + k0 + lk];
            short8 bl = *(const short8*)&w_lo[n * 800 + k0 + lk];
            acc[0][nt] = __builtin_amdgcn_mfma_f32_16x16x32_bf16(a0, bh, acc[0][nt], 0, 0, 0);
            acc[0][nt] = __builtin_amdgcn_mfma_f32_16x16x32_bf16(a0, bl, acc[0][nt], 0, 0, 0);
            acc[1][nt] = __builtin_amdgcn_mfma_f32_16x16x32_bf16(a1, bh, acc[1][nt], 0, 0, 0);
            acc[1][nt] = __builtin_amdgcn_mfma_f32_16x16x32_bf16(a1, bl, acc[1][nt], 0, 0, 0);
        }
    }

    // epilogue: +bias, bf16 store, squared norms from the ROUNDED values
    float ebias[8];
    #pragma unroll
    for (int nt = 0; nt < 8; ++nt) ebias[nt] = encb[w * 128 + nt * 16 + lr];

    #pragma unroll
    for (int mt = 0; mt < 2; ++mt) {
        float sq[4] = {0.f, 0.f, 0.f, 0.f};
        #pragma unroll
        for (int nt = 0; nt < 8; ++nt) {
            int e = w * 128 + nt * 16 + lr;
            #pragma unroll
            for (int r = 0; r < 4; ++r) {
                int row_l = mt * 16 + (lane >> 4) * 4 + r;
                float v = acc[mt][nt][r] + ebias[nt];
                ushort_t hb = f2bf(v);
                float vb = bf2f(hb);
                sq[r] += vb * vb;
                enc_out[(base + row_l) * 512 + e] = hb;
            }
        }
        #pragma unroll
        for (int r = 0; r < 4; ++r)
            atomicAdd(&s_csq[mt * 16 + (lane >> 4) * 4 + r], sq[r]);
    }
    __syncthreads();
    if (t < 32) sq_out[base + t] = s_csq[t];
}

// ---------------------------------------------------------------------------
// Distance + binning. Block: 64 q x 256 c, MFMA over K=512 (8 chunks of 64).
// Wave w covers c-subrange [w*64, w*64+64).
// ---------------------------------------------------------------------------
__global__ __launch_bounds__(256) void dist_kernel(
    const ushort_t* __restrict__ xe,   // [1024][512] bf16
    const ushort_t* __restrict__ ce,   // [100000][512] bf16
    const float*    __restrict__ xsq,  // [1024]
    const float*    __restrict__ csq,  // [100000]
    const int*      __restrict__ cy,   // [100000]
    float*          __restrict__ gbins)// [1024][10]
{
    __shared__ __align__(16) ushort_t s_xe[64 * 72];    //  9216 B (stride 72: 2-way only)
    __shared__ __align__(16) ushort_t s_ce[256 * 72];   // 36864 B
    __shared__ float s_bins[640];
    __shared__ float s_xsq[64];
    __shared__ float s_csq[256];
    __shared__ int   s_y[256];

    const int t = threadIdx.x;
    const int qbase = blockIdx.x * 64;
    const long cbase = (long)blockIdx.y * 256;

    for (int i = t; i < 640; i += 256) s_bins[i] = 0.f;
    if (t < 64) s_xsq[t] = xsq[qbase + t];
    {
        long jc = cbase + t;
        bool ok = jc < N_CAND;
        s_y[t]   = ok ? cy[jc] : -1;
        s_csq[t] = ok ? csq[jc] : 0.f;
    }

    const int lane = t & 63, w = t >> 6;
    const int lr = lane & 15;
    const int lk = (lane >> 4) * 8;

    f32x4 zero4 = {0.f, 0.f, 0.f, 0.f};
    f32x4 acc[4][4];
    #pragma unroll
    for (int mt = 0; mt < 4; ++mt)
        #pragma unroll
        for (int nt = 0; nt < 4; ++nt) acc[mt][nt] = zero4;

    for (int kc = 0; kc < 8; ++kc) {
        __syncthreads();                  // staging may overwrite prev chunk
        const int k0 = kc * 64;
        #pragma unroll
        for (int s = 0; s < 2; ++s) {     // stage xe 64x64 bf16
            int idx = t + 256 * s;
            int row = idx >> 3, seg = idx & 7;
            *(uint4*)&s_xe[row * 72 + seg * 8] =
                *(const uint4*)&xe[(size_t)(qbase + row) * 512 + k0 + seg * 8];
        }
        #pragma unroll
        for (int s = 0; s < 8; ++s) {     // stage ce 256x64 bf16 (zero OOB)
            int idx = t + 256 * s;
            int row = idx >> 3, seg = idx & 7;
            long jc = cbase + row;
            uint4 v = {0u, 0u, 0u, 0u};
            if (jc < N_CAND)
                v = *(const uint4*)&ce[jc * 512 + k0 + seg * 8];
            *(uint4*)&s_ce[row * 72 + seg * 8] = v;
        }
        __syncthreads();

        #pragma unroll
        for (int kk = 0; kk < 2; ++kk) {
            const int ko = kk * 32 + lk;
            short8 a[4], b[4];
            #pragma unroll
            for (int mt = 0; mt < 4; ++mt)
                a[mt] = *(const short8*)&s_xe[(mt * 16 + lr) * 72 + ko];
            #pragma unroll
            for (int nt = 0; nt < 4; ++nt)
                b[nt] = *(const short8*)&s_ce[(w * 64 + nt * 16 + lr) * 72 + ko];
            #pragma unroll
            for (int mt = 0; mt < 4; ++mt)
                #pragma unroll
                for (int nt = 0; nt < 4; ++nt)
                    acc[mt][nt] = __builtin_amdgcn_mfma_f32_16x16x32_bf16(
                        a[mt], b[nt], acc[mt][nt], 0, 0, 0);
        }
    }

    // epilogue: d = sqrt(|x|^2 + |c|^2 - 2 dot); bin exp(-d) by class
    #pragma unroll
    for (int nt = 0; nt < 4; ++nt) {
        int c_l = w * 64 + nt * 16 + lr;
        int cls = s_y[c_l];
        if (cls < 0) continue;
        float cq = s_csq[c_l];
        #pragma unroll
        for (int mt = 0; mt < 4; ++mt) {
            #pragma unroll
            for (int r = 0; r < 4; ++r) {
                int q_l = mt * 16 + (lane >> 4) * 4 + r;
                float sqv = s_xsq[q_l] + cq - 2.f * acc[mt][nt][r];
                float d = sqrtf(fmaxf(sqv, 1e-12f));
                atomicAdd(&s_bins[q_l * 10 + cls], __expf(-d));
            }
        }
    }
    __syncthreads();
    for (int i = t; i < 640; i += 256)
        atomicAdd(&gbins[(size_t)(qbase + i / 10) * 10 + (i % 10)], s_bins[i]);
}

// ---------------------------------------------------------------------------
__global__ __launch_bounds__(256) void final_kernel(
    const float* __restrict__ gbins, float* __restrict__ out)
{
    int q = blockIdx.x * 256 + threadIdx.x;
    if (q >= N_Q) return;
    float b[10], Z = 0.f;
    #pragma unroll
    for (int c = 0; c < 10; ++c) { b[c] = gbins[q * 10 + c]; Z += b[c]; }
    float inv = 1.f / Z;
    #pragma unroll
    for (int c = 0; c < 10; ++c)
        out[q * 10 + c] = logf(b[c] * inv + 1e-7f);
}

// ---------------------------------------------------------------------------
extern "C" void kernel_launch(void* const* d_in, const int* in_sizes, int n_in,
                              void* d_out, int out_size, void* d_ws, size_t ws_size,
                              hipStream_t stream) {
    const float* x  = (const float*)d_in[0];
    const float* cx = (const float*)d_in[1];
    const int*   cy = (const int*)d_in[2];
    const float* fr = (const float*)d_in[3];
    const float* pw = (const float*)d_in[4];
    const float* pb = (const float*)d_in[5];
    const float* ew = (const float*)d_in[6];
    const float* eb = (const float*)d_in[7];
    float* out = (float*)d_out;

    char* ws = (char*)d_ws;
    ushort_t* ce   = (ushort_t*)(ws);                 // 102,400,000 B
    ushort_t* xe   = (ushort_t*)(ws + 102400000);     //   1,048,576 B
    float*    xsq  = (float*)   (ws + 103448576);     //       4,096 B
    float*    csq  = (float*)   (ws + 103452672);     //     400,000 B
    float*    gbin = (float*)   (ws + 103852672);     //      40,960 B
    ushort_t* w_hi = (ushort_t*)(ws + 103893632);     //     819,200 B
    ushort_t* w_lo = (ushort_t*)(ws + 104712832);     //     819,200 B (tot ~100.6 MiB)

    hipMemsetAsync(gbin, 0, N_Q * 10 * sizeof(float), stream);
    wsplit_kernel<<<1600, 256, 0, stream>>>(ew, w_hi, w_lo);
    encode_kernel<<<N_CAND / 32, 256, 0, stream>>>(cx, fr, pw, pb, w_hi, w_lo, eb, ce, csq);
    encode_kernel<<<N_Q / 32,    256, 0, stream>>>(x,  fr, pw, pb, w_hi, w_lo, eb, xe, xsq);
    dist_kernel<<<dim3(16, (N_CAND + 255) / 256), 256, 0, stream>>>(xe, ce, xsq, csq, cy, gbin);
    final_kernel<<<4, 256, 0, stream>>>(gbin, out);
}

// Round 3
// 1570.138 us; speedup vs baseline: 7.1348x; 1.3323x over previous
//
#include <hip/hip_runtime.h>

// ModernNCA fused pipeline, round 3:
// - encode Phase A (PLR) rewritten as in-register MFMA GEMM (was LDS-read bound).
// - dist re-tiled 256q x 128c to cut ce L3 traffic 4x.

#define TWO_PI 6.283185307179586f
#define N_CAND 100000
#define N_CPAD 100096           // 782 * 128
#define N_Q    1024

typedef unsigned short ushort_t;
typedef unsigned int uint_t;
typedef __attribute__((ext_vector_type(8))) short short8;   // 8 bf16 = 4 VGPRs
typedef __attribute__((ext_vector_type(4))) float f32x4;

__device__ __forceinline__ float bf2f(ushort_t h) {
    union { uint_t u; float f; } c; c.u = ((uint_t)h) << 16; return c.f;
}
__device__ __forceinline__ ushort_t f2bf(float f) {
    union { float f; uint_t u; } c; c.f = f;
    uint_t u = c.u + 0x7fffu + ((c.u >> 16) & 1u);   // RNE; inputs finite
    return (ushort_t)(u >> 16);
}

// ---------------------------------------------------------------------------
// Prepass: encw[512][776] fp32 -> w_hi/w_lo bf16 [512][800] (zero pad tail).
// ---------------------------------------------------------------------------
__global__ __launch_bounds__(256) void wsplit_kernel(
    const float* __restrict__ encw, ushort_t* __restrict__ w_hi,
    ushort_t* __restrict__ w_lo)
{
    int idx = blockIdx.x * 256 + threadIdx.x;     // 512*800 = 409600
    if (idx >= 512 * 800) return;
    int n = idx / 800, k = idx - n * 800;
    float w = (k < 776) ? encw[n * 776 + k] : 0.f;
    ushort_t h = f2bf(w);
    w_hi[idx] = h;
    w_lo[idx] = f2bf(w - bf2f(h));
}

// Zero the 96 pad rows of ce so dist MFMA reads 0 there.
__global__ __launch_bounds__(256) void pad_kernel(ushort_t* __restrict__ ce)
{
    int i = blockIdx.x * 256 + threadIdx.x;       // 96*512/8 = 6144 uint4
    if (i < 6144) {
        uint4 z = {0u, 0u, 0u, 0u};
        ((uint4*)(ce + (size_t)N_CAND * 512))[i] = z;
    }
}

// ---------------------------------------------------------------------------
// Encoder: 32 rows/block.
// Phase A: PLR as MFMA: A[m=(row,n)][k=32] (k<16 cos, k>=16 sin) built in regs,
//          B = plr_w hi/lo bf16 fragments in regs. C -> s_feat bf16 [32][808].
// Phase B: MFMA feat @ (w_hi + w_lo)^T, 4 waves x 128 cols (unchanged from R2).
// ---------------------------------------------------------------------------
__global__ __launch_bounds__(256) void encode_kernel(
    const float* __restrict__ vin,    // [nrows][32]
    const float* __restrict__ freq,   // [24][16]
    const float* __restrict__ plrw,   // [32][32]
    const float* __restrict__ plrb,   // [32]
    const ushort_t* __restrict__ w_hi,// [512][800] bf16
    const ushort_t* __restrict__ w_lo,// [512][800] bf16
    const float* __restrict__ encb,   // [512]
    ushort_t*    __restrict__ enc_out,// [nrows][512] bf16
    float*       __restrict__ sq_out) // [nrows]
{
    __shared__ float    s_cx[32 * 32];            //  4096 B
    __shared__ float    s_freq[24 * 16];          //  1536 B (premult by 2pi)
    __shared__ float    s_csq[32];
    __shared__ __align__(16) ushort_t s_feat[32 * 808];  // 51712 B

    const int t = threadIdx.x;
    const long base = (long)blockIdx.x * 32;
    const int lane = t & 63, w = t >> 6;
    const int lr = lane & 15;
    const int g  = lane >> 4;

    ((float4*)s_cx)[t] = ((const float4*)(vin + base * 32))[t];
    if (t < 96) {
        float4 f = ((const float4*)freq)[t];
        f.x *= TWO_PI; f.y *= TWO_PI; f.z *= TWO_PI; f.w *= TWO_PI;
        ((float4*)s_freq)[t] = f;
    }
    if (t < 32) s_csq[t] = 0.f;
    {   // zero-pad feat K-tail [776,808)
        int row = t >> 3, kk = 776 + (t & 7) * 4;
        ushort_t* p = &s_feat[row * 808 + kk];
        p[0] = 0; p[1] = 0; p[2] = 0; p[3] = 0;
    }

    // ---- PLR B-fragments (registers, whole block): B[k][e] = plrw[e][k] ----
    // lane (g,lr) holds B[8g+j][e'], e' = lr (tile0) / 16+lr (tile1)
    short8 pbh[2], pbl[2];
    float pbias[2];
    #pragma unroll
    for (int n = 0; n < 2; ++n) {
        int e = n * 16 + lr;
        const float* pr = plrw + e * 32 + g * 8;
        float wv[8];
        *(float4*)&wv[0] = *(const float4*)pr;
        *(float4*)&wv[4] = *(const float4*)(pr + 4);
        #pragma unroll
        for (int j = 0; j < 8; ++j) {
            ushort_t h = f2bf(wv[j]);
            pbh[n][j] = (short)h;
            pbl[n][j] = (short)f2bf(wv[j] - bf2f(h));
        }
        pbias[n] = plrb[e];
    }
    __syncthreads();

    // ---- Phase A: 48 M-tiles of 16 pairs; wave w does tiles [12w, 12w+12) ----
    const bool use_sin = (lane >= 32);
    const int f0 = (g & 1) * 8;
    for (int i = 0; i < 12; ++i) {
        const int tile = w * 12 + i;
        // A-frag: m = tile*16 + lr
        const int m_a = tile * 16 + lr;
        const int rowa = m_a / 24, na = m_a - rowa * 24;
        const float v = s_cx[rowa * 32 + na];
        float ang[8];
        *(float4*)&ang[0] = *(const float4*)&s_freq[na * 16 + f0];
        *(float4*)&ang[4] = *(const float4*)&s_freq[na * 16 + f0 + 4];
        short8 af;
        #pragma unroll
        for (int j = 0; j < 8; ++j) {
            float sv, cv;
            __sincosf(ang[j] * v, &sv, &cv);
            af[j] = (short)f2bf(use_sin ? sv : cv);
        }
        f32x4 c0 = {0.f, 0.f, 0.f, 0.f}, c1 = {0.f, 0.f, 0.f, 0.f};
        c0 = __builtin_amdgcn_mfma_f32_16x16x32_bf16(af, pbh[0], c0, 0, 0, 0);
        c0 = __builtin_amdgcn_mfma_f32_16x16x32_bf16(af, pbl[0], c0, 0, 0, 0);
        c1 = __builtin_amdgcn_mfma_f32_16x16x32_bf16(af, pbh[1], c1, 0, 0, 0);
        c1 = __builtin_amdgcn_mfma_f32_16x16x32_bf16(af, pbl[1], c1, 0, 0, 0);
        // C: col = lr (=e within tile), rows = g*4 + r
        #pragma unroll
        for (int r = 0; r < 4; ++r) {
            const int m_c = tile * 16 + g * 4 + r;
            const int rowc = m_c / 24, nc = m_c - rowc * 24;
            s_feat[rowc * 808 + nc * 32 + lr]      = f2bf(fmaxf(c0[r] + pbias[0], 0.f));
            s_feat[rowc * 808 + nc * 32 + 16 + lr] = f2bf(fmaxf(c1[r] + pbias[1], 0.f));
        }
    }
    { // v_cat passthrough
        int c = t >> 3, j = t & 7;
        s_feat[c * 808 + 768 + j] = f2bf(s_cx[c * 32 + 24 + j]);
    }
    __syncthreads();

    // ---- Phase B: wave w covers e in [w*128, w*128+128) ----
    const int lk = g * 8;
    f32x4 zero4 = {0.f, 0.f, 0.f, 0.f};
    f32x4 acc[2][8];
    #pragma unroll
    for (int mt = 0; mt < 2; ++mt)
        #pragma unroll
        for (int nt = 0; nt < 8; ++nt) acc[mt][nt] = zero4;

    for (int kc = 0; kc < 25; ++kc) {
        const int k0 = kc * 32;
        short8 a0 = *(const short8*)&s_feat[lr * 808 + k0 + lk];
        short8 a1 = *(const short8*)&s_feat[(16 + lr) * 808 + k0 + lk];
        #pragma unroll
        for (int nt = 0; nt < 8; ++nt) {
            const size_t n = (size_t)(w * 128 + nt * 16 + lr);
            short8 bh = *(const short8*)&w_hi[n * 800 + k0 + lk];
            short8 bl = *(const short8*)&w_lo[n * 800 + k0 + lk];
            acc[0][nt] = __builtin_amdgcn_mfma_f32_16x16x32_bf16(a0, bh, acc[0][nt], 0, 0, 0);
            acc[0][nt] = __builtin_amdgcn_mfma_f32_16x16x32_bf16(a0, bl, acc[0][nt], 0, 0, 0);
            acc[1][nt] = __builtin_amdgcn_mfma_f32_16x16x32_bf16(a1, bh, acc[1][nt], 0, 0, 0);
            acc[1][nt] = __builtin_amdgcn_mfma_f32_16x16x32_bf16(a1, bl, acc[1][nt], 0, 0, 0);
        }
    }

    float ebias[8];
    #pragma unroll
    for (int nt = 0; nt < 8; ++nt) ebias[nt] = encb[w * 128 + nt * 16 + lr];

    #pragma unroll
    for (int mt = 0; mt < 2; ++mt) {
        float sq[4] = {0.f, 0.f, 0.f, 0.f};
        #pragma unroll
        for (int nt = 0; nt < 8; ++nt) {
            int e = w * 128 + nt * 16 + lr;
            #pragma unroll
            for (int r = 0; r < 4; ++r) {
                int row_l = mt * 16 + g * 4 + r;
                float vv = acc[mt][nt][r] + ebias[nt];
                ushort_t hb = f2bf(vv);
                float vb = bf2f(hb);
                sq[r] += vb * vb;
                enc_out[(base + row_l) * 512 + e] = hb;
            }
        }
        #pragma unroll
        for (int r = 0; r < 4; ++r)
            atomicAdd(&s_csq[mt * 16 + g * 4 + r], sq[r]);
    }
    __syncthreads();
    if (t < 32) sq_out[base + t] = s_csq[t];
}

// ---------------------------------------------------------------------------
// Distance + binning. Block: 256 q x 128 c (grid 4 x 782), K=512 in 8 chunks.
// Wave w covers q-slice [w*64, w*64+64), all 128 c.
// ---------------------------------------------------------------------------
__global__ __launch_bounds__(256) void dist_kernel(
    const ushort_t* __restrict__ xe,   // [1024][512] bf16
    const ushort_t* __restrict__ ce,   // [100096][512] bf16 (pad rows zero)
    const float*    __restrict__ xsq,  // [1024]
    const float*    __restrict__ csq,  // [100000]
    const int*      __restrict__ cy,   // [100000]
    float*          __restrict__ gbins)// [1024][10]
{
    __shared__ __align__(16) ushort_t s_xe[256 * 72];   // 36864 B
    __shared__ __align__(16) ushort_t s_ce[128 * 72];   // 18432 B
    __shared__ float s_bins[2560];                      // 10240 B
    __shared__ float s_xsq[256];
    __shared__ float s_csq[128];
    __shared__ int   s_y[128];

    const int t = threadIdx.x;
    const int qbase = blockIdx.x * 256;
    const long cbase = (long)blockIdx.y * 128;

    for (int i = t; i < 2560; i += 256) s_bins[i] = 0.f;
    s_xsq[t] = xsq[qbase + t];
    if (t < 128) {
        long jc = cbase + t;
        bool ok = jc < N_CAND;
        s_y[t]   = ok ? cy[jc] : 0;
        s_csq[t] = ok ? csq[jc] : 1e30f;   // pad: exp(-1e15) = 0
    }

    const int lane = t & 63, w = t >> 6;
    const int lr = lane & 15, g = lane >> 4;
    const int lk = g * 8;

    f32x4 zero4 = {0.f, 0.f, 0.f, 0.f};
    f32x4 acc[4][8];
    #pragma unroll
    for (int mt = 0; mt < 4; ++mt)
        #pragma unroll
        for (int nt = 0; nt < 8; ++nt) acc[mt][nt] = zero4;

    for (int kc = 0; kc < 8; ++kc) {
        __syncthreads();
        const int k0 = kc * 64;
        #pragma unroll
        for (int s = 0; s < 8; ++s) {     // stage xe 256x64 bf16
            int idx = t + 256 * s;
            int row = idx >> 3, seg = idx & 7;
            *(uint4*)&s_xe[row * 72 + seg * 8] =
                *(const uint4*)&xe[(size_t)(qbase + row) * 512 + k0 + seg * 8];
        }
        #pragma unroll
        for (int s = 0; s < 4; ++s) {     // stage ce 128x64 bf16 (pad rows zeroed)
            int idx = t + 256 * s;
            int row = idx >> 3, seg = idx & 7;
            *(uint4*)&s_ce[row * 72 + seg * 8] =
                *(const uint4*)&ce[(cbase + row) * 512 + k0 + seg * 8];
        }
        __syncthreads();

        #pragma unroll
        for (int kk = 0; kk < 2; ++kk) {
            const int ko = kk * 32 + lk;
            short8 a[4], b[8];
            #pragma unroll
            for (int mt = 0; mt < 4; ++mt)
                a[mt] = *(const short8*)&s_xe[(w * 64 + mt * 16 + lr) * 72 + ko];
            #pragma unroll
            for (int nt = 0; nt < 8; ++nt)
                b[nt] = *(const short8*)&s_ce[(nt * 16 + lr) * 72 + ko];
            #pragma unroll
            for (int mt = 0; mt < 4; ++mt)
                #pragma unroll
                for (int nt = 0; nt < 8; ++nt)
                    acc[mt][nt] = __builtin_amdgcn_mfma_f32_16x16x32_bf16(
                        a[mt], b[nt], acc[mt][nt], 0, 0, 0);
        }
    }

    // epilogue: d = sqrt(|x|^2 + |c|^2 - 2 dot); bin exp(-d) by class
    float xq[4][4];
    #pragma unroll
    for (int mt = 0; mt < 4; ++mt)
        #pragma unroll
        for (int r = 0; r < 4; ++r)
            xq[mt][r] = s_xsq[w * 64 + mt * 16 + g * 4 + r];

    #pragma unroll
    for (int nt = 0; nt < 8; ++nt) {
        int c_l = nt * 16 + lr;
        int cls = s_y[c_l];
        float cq = s_csq[c_l];
        #pragma unroll
        for (int mt = 0; mt < 4; ++mt) {
            #pragma unroll
            for (int r = 0; r < 4; ++r) {
                float sqv = xq[mt][r] + cq - 2.f * acc[mt][nt][r];
                float d = sqrtf(fmaxf(sqv, 1e-12f));
                atomicAdd(&s_bins[(w * 64 + mt * 16 + g * 4 + r) * 10 + cls], __expf(-d));
            }
        }
    }
    __syncthreads();
    for (int i = t; i < 2560; i += 256)
        atomicAdd(&gbins[(size_t)(qbase + i / 10) * 10 + (i % 10)], s_bins[i]);
}

// ---------------------------------------------------------------------------
__global__ __launch_bounds__(256) void final_kernel(
    const float* __restrict__ gbins, float* __restrict__ out)
{
    int q = blockIdx.x * 256 + threadIdx.x;
    if (q >= N_Q) return;
    float b[10], Z = 0.f;
    #pragma unroll
    for (int c = 0; c < 10; ++c) { b[c] = gbins[q * 10 + c]; Z += b[c]; }
    float inv = 1.f / Z;
    #pragma unroll
    for (int c = 0; c < 10; ++c)
        out[q * 10 + c] = logf(b[c] * inv + 1e-7f);
}

// ---------------------------------------------------------------------------
extern "C" void kernel_launch(void* const* d_in, const int* in_sizes, int n_in,
                              void* d_out, int out_size, void* d_ws, size_t ws_size,
                              hipStream_t stream) {
    const float* x  = (const float*)d_in[0];
    const float* cx = (const float*)d_in[1];
    const int*   cy = (const int*)d_in[2];
    const float* fr = (const float*)d_in[3];
    const float* pw = (const float*)d_in[4];
    const float* pb = (const float*)d_in[5];
    const float* ew = (const float*)d_in[6];
    const float* eb = (const float*)d_in[7];
    float* out = (float*)d_out;

    char* ws = (char*)d_ws;
    ushort_t* ce   = (ushort_t*)(ws);                 // 102,498,304 B (100096 rows)
    ushort_t* xe   = (ushort_t*)(ws + 102498304);     //   1,048,576 B
    float*    xsq  = (float*)   (ws + 103546880);     //       4,096 B
    float*    csq  = (float*)   (ws + 103550976);     //     400,000 B
    float*    gbin = (float*)   (ws + 103950976);     //      40,960 B
    ushort_t* w_hi = (ushort_t*)(ws + 103991936);     //     819,200 B
    ushort_t* w_lo = (ushort_t*)(ws + 104811136);     //     819,200 B (tot ~100.7 MiB)

    hipMemsetAsync(gbin, 0, N_Q * 10 * sizeof(float), stream);
    wsplit_kernel<<<1600, 256, 0, stream>>>(ew, w_hi, w_lo);
    pad_kernel<<<24, 256, 0, stream>>>(ce);
    encode_kernel<<<N_CAND / 32, 256, 0, stream>>>(cx, fr, pw, pb, w_hi, w_lo, eb, ce, csq);
    encode_kernel<<<N_Q / 32,    256, 0, stream>>>(x,  fr, pw, pb, w_hi, w_lo, eb, xe, xsq);
    dist_kernel<<<dim3(4, N_CPAD / 128), 256, 0, stream>>>(xe, ce, xsq, csq, cy, gbin);
    final_kernel<<<4, 256, 0, stream>>>(gbin, out);
}

// Round 4
// 1198.606 us; speedup vs baseline: 9.3464x; 1.3100x over previous
//
#include <hip/hip_runtime.h>

// ModernNCA round 4: m97-style GEMMs with global_load_lds staging.
// plr_kernel -> feat (global, bf16, slab-buffered), enc_gemm_kernel (128x128
// tiles, K=832, W hi/lo), dist_kernel (ce via glds, xe direct-to-reg).

#define TWO_PI 6.283185307179586f
#define N_CAND 100000
#define N_CPAD 100096           // 782 * 128
#define N_Q    1024
#define KENC   832              // 776 padded to 13*64

typedef unsigned short ushort_t;
typedef unsigned int uint_t;
typedef __attribute__((ext_vector_type(8))) short short8;   // 8 bf16
typedef __attribute__((ext_vector_type(4))) float f32x4;

__device__ __forceinline__ float bf2f(ushort_t h) {
    union { uint_t u; float f; } c; c.u = ((uint_t)h) << 16; return c.f;
}
__device__ __forceinline__ ushort_t f2bf(float f) {
    union { float f; uint_t u; } c; c.f = f;
    uint_t u = c.u + 0x7fffu + ((c.u >> 16) & 1u);   // RNE; inputs finite
    return (ushort_t)(u >> 16);
}

// async global->LDS, 16B per lane; lds dest = wave-uniform base + lane*16
__device__ __forceinline__ void glds16(const void* g, void* l) {
    __builtin_amdgcn_global_load_lds(
        (const __attribute__((address_space(1))) void*)g,
        (__attribute__((address_space(3))) void*)l, 16, 0, 0);
}

// ---------------------------------------------------------------------------
// Prepass: encw[512][776] fp32 -> w_hi/w_lo bf16 [512][832] (zero pad tail).
// ---------------------------------------------------------------------------
__global__ __launch_bounds__(256) void wsplit_kernel(
    const float* __restrict__ encw, ushort_t* __restrict__ w_hi,
    ushort_t* __restrict__ w_lo)
{
    int idx = blockIdx.x * 256 + threadIdx.x;     // 512*832 = 425984
    if (idx >= 512 * KENC) return;
    int n = idx / KENC, k = idx - n * KENC;
    float w = (k < 776) ? encw[n * 776 + k] : 0.f;
    ushort_t h = f2bf(w);
    w_hi[idx] = h;
    w_lo[idx] = f2bf(w - bf2f(h));
}

// ---------------------------------------------------------------------------
// PLR: 32 rows/block -> feat_out[local_row][832] bf16 in global.
// In-register MFMA PLR (R3-verified), guarded source reads for pad rows.
// ---------------------------------------------------------------------------
__global__ __launch_bounds__(256) void plr_kernel(
    const float* __restrict__ vin,    // [nsrc][32]
    int nsrc, long src_base,
    const float* __restrict__ freq,   // [24][16]
    const float* __restrict__ plrw,   // [32][32]
    const float* __restrict__ plrb,   // [32]
    ushort_t*    __restrict__ feat_out) // slab-local [rows][832]
{
    __shared__ float s_cx[32 * 32];               //  4096 B
    __shared__ float s_freq[24 * 16];             //  1536 B (premult 2pi)
    __shared__ __align__(16) ushort_t s_feat[32 * KENC];  // 53248 B

    const int t = threadIdx.x;
    const long lbase = (long)blockIdx.x * 32;     // slab-local row base
    const long gbase = src_base + lbase;          // source row base
    const int lane = t & 63, w = t >> 6;
    const int lr = lane & 15, g = lane >> 4;

    {   // guarded staging: pad rows duplicate last real row (finite junk)
        long row = gbase + (t >> 3);
        if (row > (long)nsrc - 1) row = nsrc - 1;
        ((float4*)s_cx)[t] = ((const float4*)(vin + row * 32))[t & 7];
    }
    if (t < 96) {
        float4 f = ((const float4*)freq)[t];
        f.x *= TWO_PI; f.y *= TWO_PI; f.z *= TWO_PI; f.w *= TWO_PI;
        ((float4*)s_freq)[t] = f;
    }
    // zero K-tail [776,832): 32 rows x 56 shorts = 896 dwords
    for (int i = t; i < 896; i += 256) {
        int row = i / 28, o = (i - row * 28) * 2;
        *(uint_t*)&s_feat[row * KENC + 776 + o] = 0u;
    }

    // PLR B-fragments in registers: B[k][e] = plrw[e][k], hi/lo split
    short8 pbh[2], pbl[2];
    float pbias[2];
    #pragma unroll
    for (int n = 0; n < 2; ++n) {
        int e = n * 16 + lr;
        const float* pr = plrw + e * 32 + g * 8;
        float wv[8];
        *(float4*)&wv[0] = *(const float4*)pr;
        *(float4*)&wv[4] = *(const float4*)(pr + 4);
        #pragma unroll
        for (int j = 0; j < 8; ++j) {
            ushort_t h = f2bf(wv[j]);
            pbh[n][j] = (short)h;
            pbl[n][j] = (short)f2bf(wv[j] - bf2f(h));
        }
        pbias[n] = plrb[e];
    }
    __syncthreads();

    // 48 M-tiles of 16 (row,n) pairs; wave w does tiles [12w, 12w+12)
    const bool use_sin = (lane >= 32);
    const int f0 = (g & 1) * 8;
    for (int i = 0; i < 12; ++i) {
        const int tile = w * 12 + i;
        const int m_a = tile * 16 + lr;
        const int rowa = m_a / 24, na = m_a - rowa * 24;
        const float v = s_cx[rowa * 32 + na];
        float ang[8];
        *(float4*)&ang[0] = *(const float4*)&s_freq[na * 16 + f0];
        *(float4*)&ang[4] = *(const float4*)&s_freq[na * 16 + f0 + 4];
        short8 af;
        #pragma unroll
        for (int j = 0; j < 8; ++j) {
            float sv, cv;
            __sincosf(ang[j] * v, &sv, &cv);
            af[j] = (short)f2bf(use_sin ? sv : cv);
        }
        f32x4 c0 = {0.f, 0.f, 0.f, 0.f}, c1 = {0.f, 0.f, 0.f, 0.f};
        c0 = __builtin_amdgcn_mfma_f32_16x16x32_bf16(af, pbh[0], c0, 0, 0, 0);
        c0 = __builtin_amdgcn_mfma_f32_16x16x32_bf16(af, pbl[0], c0, 0, 0, 0);
        c1 = __builtin_amdgcn_mfma_f32_16x16x32_bf16(af, pbh[1], c1, 0, 0, 0);
        c1 = __builtin_amdgcn_mfma_f32_16x16x32_bf16(af, pbl[1], c1, 0, 0, 0);
        #pragma unroll
        for (int r = 0; r < 4; ++r) {
            const int m_c = tile * 16 + g * 4 + r;
            const int rowc = m_c / 24, nc = m_c - rowc * 24;
            s_feat[rowc * KENC + nc * 32 + lr]      = f2bf(fmaxf(c0[r] + pbias[0], 0.f));
            s_feat[rowc * KENC + nc * 32 + 16 + lr] = f2bf(fmaxf(c1[r] + pbias[1], 0.f));
        }
    }
    { // v_cat passthrough
        int c = t >> 3, j = t & 7;
        s_feat[c * KENC + 768 + j] = f2bf(s_cx[c * 32 + 24 + j]);
    }
    __syncthreads();

    // vectorized copy-out: 32*832*2B = 3328 uint4
    uint4* dst = (uint4*)(feat_out + lbase * KENC);
    const uint4* src = (const uint4*)s_feat;
    #pragma unroll
    for (int i = 0; i < 13; ++i)
        dst[t + 256 * i] = src[t + 256 * i];
}

// ---------------------------------------------------------------------------
// Encoder GEMM: out[m][n] = feat[m][.] @ (w_hi + w_lo)[n][.]^T + encb.
// 128x128 tile, BK=64, glds staging, 4 waves 2x2 of 64x64.
// Writes bf16 enc_out rows + atomically accumulates squared norms.
// ---------------------------------------------------------------------------
__global__ __launch_bounds__(256) void enc_gemm_kernel(
    const ushort_t* __restrict__ feat,   // slab-local [rows][832]
    long mbase,                          // global row offset of slab
    const ushort_t* __restrict__ w_hi,   // [512][832]
    const ushort_t* __restrict__ w_lo,   // [512][832]
    const float* __restrict__ encb,      // [512]
    ushort_t* __restrict__ enc_out,      // [.][512]
    float*    __restrict__ sq_out)       // [.]
{
    __shared__ __align__(16) ushort_t s_A [128 * 64];   // 16384 B
    __shared__ __align__(16) ushort_t s_Bh[128 * 64];   // 16384 B
    __shared__ __align__(16) ushort_t s_Bl[128 * 64];   // 16384 B
    __shared__ float s_sq[128];

    const int t = threadIdx.x;
    const long mloc = (long)blockIdx.x * 128;
    const int nbase = blockIdx.y * 128;
    const int lane = t & 63, w = t >> 6;
    const int lr = lane & 15, g = lane >> 4;
    const int mrow = (w & 1) * 64, ncol = (w >> 1) * 64;
    const int wu = t & ~63;               // wave-uniform thread base

    if (t < 128) s_sq[t] = 0.f;

    f32x4 zero4 = {0.f, 0.f, 0.f, 0.f};
    f32x4 acc[4][4];
    #pragma unroll
    for (int mt = 0; mt < 4; ++mt)
        #pragma unroll
        for (int nt = 0; nt < 4; ++nt) acc[mt][nt] = zero4;

    for (int kc = 0; kc < 13; ++kc) {
        const int k0 = kc * 64;
        __syncthreads();                  // prev chunk fully consumed
        #pragma unroll
        for (int s = 0; s < 4; ++s) {
            int idx = t + 256 * s;
            int row = idx >> 3, seg = (idx & 7) * 8;
            size_t ldso = (size_t)(wu + 256 * s) * 16;
            glds16(&feat[(mloc + row) * KENC + k0 + seg], (char*)s_A  + ldso);
            glds16(&w_hi[(size_t)(nbase + row) * KENC + k0 + seg], (char*)s_Bh + ldso);
            glds16(&w_lo[(size_t)(nbase + row) * KENC + k0 + seg], (char*)s_Bl + ldso);
        }
        __syncthreads();                  // drains vmcnt (glds) before reads
        #pragma unroll
        for (int kk = 0; kk < 2; ++kk) {
            const int ko = kk * 32 + g * 8;
            short8 a[4], bh[4], bl[4];
            #pragma unroll
            for (int mt = 0; mt < 4; ++mt)
                a[mt] = *(const short8*)&s_A[(mrow + mt * 16 + lr) * 64 + ko];
            #pragma unroll
            for (int nt = 0; nt < 4; ++nt) {
                bh[nt] = *(const short8*)&s_Bh[(ncol + nt * 16 + lr) * 64 + ko];
                bl[nt] = *(const short8*)&s_Bl[(ncol + nt * 16 + lr) * 64 + ko];
            }
            #pragma unroll
            for (int mt = 0; mt < 4; ++mt)
                #pragma unroll
                for (int nt = 0; nt < 4; ++nt) {
                    acc[mt][nt] = __builtin_amdgcn_mfma_f32_16x16x32_bf16(
                        a[mt], bh[nt], acc[mt][nt], 0, 0, 0);
                    acc[mt][nt] = __builtin_amdgcn_mfma_f32_16x16x32_bf16(
                        a[mt], bl[nt], acc[mt][nt], 0, 0, 0);
                }
        }
    }

    // epilogue: +bias, bf16 store, row-norm partials (shfl-reduce across lr)
    float bias[4];
    #pragma unroll
    for (int nt = 0; nt < 4; ++nt) bias[nt] = encb[nbase + ncol + nt * 16 + lr];

    #pragma unroll
    for (int mt = 0; mt < 4; ++mt) {
        float sqr[4] = {0.f, 0.f, 0.f, 0.f};
        #pragma unroll
        for (int nt = 0; nt < 4; ++nt) {
            #pragma unroll
            for (int r = 0; r < 4; ++r) {
                float v = acc[mt][nt][r] + bias[nt];
                ushort_t hb = f2bf(v);
                float vb = bf2f(hb);
                sqr[r] += vb * vb;
                enc_out[(mbase + mloc + mrow + mt * 16 + g * 4 + r) * 512
                        + nbase + ncol + nt * 16 + lr] = hb;
            }
        }
        #pragma unroll
        for (int r = 0; r < 4; ++r) {
            float vs = sqr[r];
            vs += __shfl_xor(vs, 1);
            vs += __shfl_xor(vs, 2);
            vs += __shfl_xor(vs, 4);
            vs += __shfl_xor(vs, 8);
            if (lr == 0) atomicAdd(&s_sq[mrow + mt * 16 + g * 4 + r], vs);
        }
    }
    __syncthreads();
    if (t < 128) atomicAdd(&sq_out[mbase + mloc + t], s_sq[t]);
}

// ---------------------------------------------------------------------------
// Distance + binning. Block 256q x 128c; ce via glds [128][64]; xe A-frags
// direct global->VGPR (L2-hot, no barrier coupling). K=512 in 8 chunks.
// ---------------------------------------------------------------------------
__global__ __launch_bounds__(256) void dist_kernel(
    const ushort_t* __restrict__ xe,   // [1024][512]
    const ushort_t* __restrict__ ce,   // [100096][512] (pad rows finite junk)
    const float*    __restrict__ xsq,  // [1024]
    const float*    __restrict__ csq,  // [100096] (pad entries unread)
    const int*      __restrict__ cy,   // [100000]
    float*          __restrict__ gbins)// [1024][10]
{
    __shared__ __align__(16) ushort_t s_ce[128 * 64];   // 16384 B
    __shared__ float s_bins[2560];                      // 10240 B
    __shared__ float s_xsq[256];
    __shared__ float s_csq[128];
    __shared__ int   s_y[128];

    const int t = threadIdx.x;
    const int qbase = blockIdx.x * 256;
    const long cbase = (long)blockIdx.y * 128;
    const int lane = t & 63, w = t >> 6;
    const int lr = lane & 15, g = lane >> 4;
    const int wu = t & ~63;

    for (int i = t; i < 2560; i += 256) s_bins[i] = 0.f;
    s_xsq[t] = xsq[qbase + t];
    if (t < 128) {
        long jc = cbase + t;
        bool ok = jc < N_CAND;
        s_y[t]   = ok ? cy[jc] : 0;
        s_csq[t] = ok ? csq[jc] : 1e30f;   // pad: d ~ 1e15 -> exp = 0
    }

    f32x4 zero4 = {0.f, 0.f, 0.f, 0.f};
    f32x4 acc[4][8];
    #pragma unroll
    for (int mt = 0; mt < 4; ++mt)
        #pragma unroll
        for (int nt = 0; nt < 8; ++nt) acc[mt][nt] = zero4;

    for (int kc = 0; kc < 8; ++kc) {
        const int k0 = kc * 64;
        __syncthreads();                  // prev chunk consumed (also covers init)
        #pragma unroll
        for (int s = 0; s < 4; ++s) {     // stage ce 128x64 via glds
            int idx = t + 256 * s;
            int row = idx >> 3, seg = (idx & 7) * 8;
            glds16(&ce[(cbase + row) * 512 + k0 + seg],
                   (char*)s_ce + (size_t)(wu + 256 * s) * 16);
        }
        // A-frags: direct global loads (xe is L2-hot; drained by the barrier)
        short8 a[2][4];
        #pragma unroll
        for (int kk = 0; kk < 2; ++kk)
            #pragma unroll
            for (int mt = 0; mt < 4; ++mt)
                a[kk][mt] = *(const short8*)
                    &xe[(size_t)(qbase + w * 64 + mt * 16 + lr) * 512 + k0 + kk * 32 + g * 8];
        __syncthreads();                  // glds + a-loads complete
        #pragma unroll
        for (int kk = 0; kk < 2; ++kk) {
            const int ko = kk * 32 + g * 8;
            short8 b[8];
            #pragma unroll
            for (int nt = 0; nt < 8; ++nt)
                b[nt] = *(const short8*)&s_ce[(nt * 16 + lr) * 64 + ko];
            #pragma unroll
            for (int mt = 0; mt < 4; ++mt)
                #pragma unroll
                for (int nt = 0; nt < 8; ++nt)
                    acc[mt][nt] = __builtin_amdgcn_mfma_f32_16x16x32_bf16(
                        a[kk][mt], b[nt], acc[mt][nt], 0, 0, 0);
        }
    }

    // epilogue: d = sqrt(|x|^2 + |c|^2 - 2 dot); bin exp(-d) by class
    float xq[4][4];
    #pragma unroll
    for (int mt = 0; mt < 4; ++mt)
        #pragma unroll
        for (int r = 0; r < 4; ++r)
            xq[mt][r] = s_xsq[w * 64 + mt * 16 + g * 4 + r];

    #pragma unroll
    for (int nt = 0; nt < 8; ++nt) {
        int c_l = nt * 16 + lr;
        int cls = s_y[c_l];
        float cq = s_csq[c_l];
        #pragma unroll
        for (int mt = 0; mt < 4; ++mt) {
            #pragma unroll
            for (int r = 0; r < 4; ++r) {
                float sqv = xq[mt][r] + cq - 2.f * acc[mt][nt][r];
                float d = sqrtf(fmaxf(sqv, 1e-12f));
                atomicAdd(&s_bins[(w * 64 + mt * 16 + g * 4 + r) * 10 + cls], __expf(-d));
            }
        }
    }
    __syncthreads();
    for (int i = t; i < 2560; i += 256)
        atomicAdd(&gbins[(size_t)(qbase + i / 10) * 10 + (i % 10)], s_bins[i]);
}

// ---------------------------------------------------------------------------
__global__ __launch_bounds__(256) void final_kernel(
    const float* __restrict__ gbins, float* __restrict__ out)
{
    int q = blockIdx.x * 256 + threadIdx.x;
    if (q >= N_Q) return;
    float b[10], Z = 0.f;
    #pragma unroll
    for (int c = 0; c < 10; ++c) { b[c] = gbins[q * 10 + c]; Z += b[c]; }
    float inv = 1.f / Z;
    #pragma unroll
    for (int c = 0; c < 10; ++c)
        out[q * 10 + c] = logf(b[c] * inv + 1e-7f);
}

// ---------------------------------------------------------------------------
extern "C" void kernel_launch(void* const* d_in, const int* in_sizes, int n_in,
                              void* d_out, int out_size, void* d_ws, size_t ws_size,
                              hipStream_t stream) {
    const float* x  = (const float*)d_in[0];
    const float* cx = (const float*)d_in[1];
    const int*   cy = (const int*)d_in[2];
    const float* fr = (const float*)d_in[3];
    const float* pw = (const float*)d_in[4];
    const float* pb = (const float*)d_in[5];
    const float* ew = (const float*)d_in[6];
    const float* eb = (const float*)d_in[7];
    float* out = (float*)d_out;

    char* ws = (char*)d_ws;
    ushort_t* ce   = (ushort_t*)(ws);                 // 102,498,304 B
    ushort_t* xe   = (ushort_t*)(ws + 102498304);     //   1,048,576 B
    float*    csq  = (float*)   (ws + 103546880);     //     400,384 B
    float*    xsq  = (float*)   (ws + 103947264);     //       4,096 B
    float*    gbin = (float*)   (ws + 103951360);     //      40,960 B
    ushort_t* w_hi = (ushort_t*)(ws + 103992320);     //     851,968 B
    ushort_t* w_lo = (ushort_t*)(ws + 104844288);     //     851,968 B
    ushort_t* fq   = (ushort_t*)(ws + 105696256);     //   1,703,936 B
    ushort_t* fc   = (ushort_t*)(ws + 107400192);     // slab buffer (rest)

    // slab sizing from available workspace (constant across calls)
    long avail = (long)ws_size - 107400192L;
    long slab = avail / (KENC * 2);
    slab &= ~127L;
    if (slab > N_CPAD) slab = N_CPAD;
    if (slab < 128)    slab = 128;

    // zero csq + xsq + gbin (contiguous)
    hipMemsetAsync(csq, 0, 445440, stream);
    wsplit_kernel<<<1664, 256, 0, stream>>>(ew, w_hi, w_lo);

    // queries
    plr_kernel<<<N_Q / 32, 256, 0, stream>>>(x, N_Q, 0, fr, pw, pb, fq);
    enc_gemm_kernel<<<dim3(N_Q / 128, 4), 256, 0, stream>>>(
        fq, 0, w_hi, w_lo, eb, xe, xsq);

    // candidates, slab by slab (stream-ordered)
    for (long sb = 0; sb < N_CPAD; sb += slab) {
        long rows = (N_CPAD - sb < slab) ? (N_CPAD - sb) : slab;
        plr_kernel<<<rows / 32, 256, 0, stream>>>(cx, N_CAND, sb, fr, pw, pb, fc);
        enc_gemm_kernel<<<dim3(rows / 128, 4), 256, 0, stream>>>(
            fc, sb, w_hi, w_lo, eb, ce, csq);
    }

    dist_kernel<<<dim3(4, N_CPAD / 128), 256, 0, stream>>>(xe, ce, xsq, csq, cy, gbin);
    final_kernel<<<4, 256, 0, stream>>>(gbin, out);
}

// Round 5
// 788.020 us; speedup vs baseline: 14.2162x; 1.5210x over previous
//
#include <hip/hip_runtime.h>

// ModernNCA round 5: class-sorted candidates kill the dist epilogue atomics.
// sort prepass (hist/prefix/scatter) -> perm,scls; plr gathers via perm;
// dist epilogue: masked register sums + shfl-reduce + ~2 atomics/thread-group.

#define TWO_PI 6.283185307179586f
#define N_CAND 100000
#define N_CPAD 100096           // 782 * 128
#define N_Q    1024
#define KENC   832              // 776 padded to 13*64

typedef unsigned short ushort_t;
typedef unsigned int uint_t;
typedef __attribute__((ext_vector_type(8))) short short8;   // 8 bf16
typedef __attribute__((ext_vector_type(4))) float f32x4;

__device__ __forceinline__ float bf2f(ushort_t h) {
    union { uint_t u; float f; } c; c.u = ((uint_t)h) << 16; return c.f;
}
__device__ __forceinline__ ushort_t f2bf(float f) {
    union { float f; uint_t u; } c; c.f = f;
    uint_t u = c.u + 0x7fffu + ((c.u >> 16) & 1u);   // RNE; inputs finite
    return (ushort_t)(u >> 16);
}

// async global->LDS, 16B per lane; lds dest = wave-uniform base + lane*16
__device__ __forceinline__ void glds16(const void* g, void* l) {
    __builtin_amdgcn_global_load_lds(
        (const __attribute__((address_space(1))) void*)g,
        (__attribute__((address_space(3))) void*)l, 16, 0, 0);
}

// ---------------------------------------------------------------------------
// Prepass: encw[512][776] fp32 -> w_hi/w_lo bf16 [512][832] (zero pad tail).
// ---------------------------------------------------------------------------
__global__ __launch_bounds__(256) void wsplit_kernel(
    const float* __restrict__ encw, ushort_t* __restrict__ w_hi,
    ushort_t* __restrict__ w_lo)
{
    int idx = blockIdx.x * 256 + threadIdx.x;
    if (idx >= 512 * KENC) return;
    int n = idx / KENC, k = idx - n * KENC;
    float w = (k < 776) ? encw[n * 776 + k] : 0.f;
    ushort_t h = f2bf(w);
    w_hi[idx] = h;
    w_lo[idx] = f2bf(w - bf2f(h));
}

// ---------------------------------------------------------------------------
// Counting sort of candidates by class (order within class is irrelevant).
// ---------------------------------------------------------------------------
__global__ __launch_bounds__(256) void hist_kernel(
    const int* __restrict__ cy, int* __restrict__ hist,
    int* __restrict__ perm, int* __restrict__ scls)
{
    __shared__ int lh[10];
    int t = threadIdx.x;
    long j = (long)blockIdx.x * 256 + t;
    if (t < 10) lh[t] = 0;
    __syncthreads();
    if (j < N_CAND) atomicAdd(&lh[cy[j]], 1);
    __syncthreads();
    if (t < 10 && lh[t] > 0) atomicAdd(&hist[t], lh[t]);
    if (blockIdx.x == 0 && t < N_CPAD - N_CAND) {   // pad positions
        perm[N_CAND + t] = 0;
        scls[N_CAND + t] = 0;   // harmless: pad p == 0 in dist
    }
}

__global__ void prefix_kernel(const int* __restrict__ hist, int* __restrict__ cursor)
{
    if (threadIdx.x == 0) {
        int run = 0;
        for (int c = 0; c < 10; ++c) { cursor[c] = run; run += hist[c]; }
    }
}

__global__ __launch_bounds__(256) void scatter_kernel(
    const int* __restrict__ cy, int* __restrict__ cursor,
    int* __restrict__ perm, int* __restrict__ scls)
{
    __shared__ int lh[10], lbase[10];
    int t = threadIdx.x;
    long j = (long)blockIdx.x * 256 + t;
    if (t < 10) lh[t] = 0;
    __syncthreads();
    int cls = -1;
    if (j < N_CAND) { cls = cy[j]; atomicAdd(&lh[cls], 1); }
    __syncthreads();
    if (t < 10 && lh[t] > 0) lbase[t] = atomicAdd(&cursor[t], lh[t]);
    __syncthreads();
    if (j < N_CAND) {
        int pos = atomicAdd(&lbase[cls], 1);
        perm[pos] = (int)j;
        scls[pos] = cls;
    }
}

// ---------------------------------------------------------------------------
// PLR: 32 rows/block -> feat_out[local_row][832] bf16. Optional perm gather.
// ---------------------------------------------------------------------------
__global__ __launch_bounds__(256) void plr_kernel(
    const float* __restrict__ vin,    // [nsrc][32]
    int nsrc, long src_base,
    const int*   __restrict__ perm,   // null -> identity (clamped)
    const float* __restrict__ freq,   // [24][16]
    const float* __restrict__ plrw,   // [32][32]
    const float* __restrict__ plrb,   // [32]
    ushort_t*    __restrict__ feat_out) // slab-local [rows][832]
{
    __shared__ float s_cx[32 * 32];
    __shared__ float s_freq[24 * 16];
    __shared__ __align__(16) ushort_t s_feat[32 * KENC];  // 53248 B

    const int t = threadIdx.x;
    const long lbase = (long)blockIdx.x * 32;
    const long gbase = src_base + lbase;
    const int lane = t & 63, w = t >> 6;
    const int lr = lane & 15, g = lane >> 4;

    {
        long idx = gbase + (t >> 3);
        long row;
        if (perm) row = perm[idx];                       // idx < N_CPAD
        else      row = (idx > (long)nsrc - 1) ? nsrc - 1 : idx;
        ((float4*)s_cx)[t] = ((const float4*)(vin + row * 32))[t & 7];
    }
    if (t < 96) {
        float4 f = ((const float4*)freq)[t];
        f.x *= TWO_PI; f.y *= TWO_PI; f.z *= TWO_PI; f.w *= TWO_PI;
        ((float4*)s_freq)[t] = f;
    }
    for (int i = t; i < 896; i += 256) {                 // zero K-tail [776,832)
        int row = i / 28, o = (i - row * 28) * 2;
        *(uint_t*)&s_feat[row * KENC + 776 + o] = 0u;
    }

    short8 pbh[2], pbl[2];
    float pbias[2];
    #pragma unroll
    for (int n = 0; n < 2; ++n) {
        int e = n * 16 + lr;
        const float* pr = plrw + e * 32 + g * 8;
        float wv[8];
        *(float4*)&wv[0] = *(const float4*)pr;
        *(float4*)&wv[4] = *(const float4*)(pr + 4);
        #pragma unroll
        for (int j = 0; j < 8; ++j) {
            ushort_t h = f2bf(wv[j]);
            pbh[n][j] = (short)h;
            pbl[n][j] = (short)f2bf(wv[j] - bf2f(h));
        }
        pbias[n] = plrb[e];
    }
    __syncthreads();

    const bool use_sin = (lane >= 32);
    const int f0 = (g & 1) * 8;
    for (int i = 0; i < 12; ++i) {
        const int tile = w * 12 + i;
        const int m_a = tile * 16 + lr;
        const int rowa = m_a / 24, na = m_a - rowa * 24;
        const float v = s_cx[rowa * 32 + na];
        float ang[8];
        *(float4*)&ang[0] = *(const float4*)&s_freq[na * 16 + f0];
        *(float4*)&ang[4] = *(const float4*)&s_freq[na * 16 + f0 + 4];
        short8 af;
        #pragma unroll
        for (int j = 0; j < 8; ++j) {
            float sv, cv;
            __sincosf(ang[j] * v, &sv, &cv);
            af[j] = (short)f2bf(use_sin ? sv : cv);
        }
        f32x4 c0 = {0.f, 0.f, 0.f, 0.f}, c1 = {0.f, 0.f, 0.f, 0.f};
        c0 = __builtin_amdgcn_mfma_f32_16x16x32_bf16(af, pbh[0], c0, 0, 0, 0);
        c0 = __builtin_amdgcn_mfma_f32_16x16x32_bf16(af, pbl[0], c0, 0, 0, 0);
        c1 = __builtin_amdgcn_mfma_f32_16x16x32_bf16(af, pbh[1], c1, 0, 0, 0);
        c1 = __builtin_amdgcn_mfma_f32_16x16x32_bf16(af, pbl[1], c1, 0, 0, 0);
        #pragma unroll
        for (int r = 0; r < 4; ++r) {
            const int m_c = tile * 16 + g * 4 + r;
            const int rowc = m_c / 24, nc = m_c - rowc * 24;
            s_feat[rowc * KENC + nc * 32 + lr]      = f2bf(fmaxf(c0[r] + pbias[0], 0.f));
            s_feat[rowc * KENC + nc * 32 + 16 + lr] = f2bf(fmaxf(c1[r] + pbias[1], 0.f));
        }
    }
    {
        int c = t >> 3, j = t & 7;
        s_feat[c * KENC + 768 + j] = f2bf(s_cx[c * 32 + 24 + j]);
    }
    __syncthreads();

    uint4* dst = (uint4*)(feat_out + lbase * KENC);
    const uint4* src = (const uint4*)s_feat;
    #pragma unroll
    for (int i = 0; i < 13; ++i)
        dst[t + 256 * i] = src[t + 256 * i];
}

// ---------------------------------------------------------------------------
// Encoder GEMM: 128x128 tile, BK=64, glds staging, W hi/lo.
// ---------------------------------------------------------------------------
__global__ __launch_bounds__(256) void enc_gemm_kernel(
    const ushort_t* __restrict__ feat,   // slab-local [rows][832]
    long mbase,
    const ushort_t* __restrict__ w_hi,
    const ushort_t* __restrict__ w_lo,
    const float* __restrict__ encb,
    ushort_t* __restrict__ enc_out,      // [.][512]
    float*    __restrict__ sq_out)       // [.]
{
    __shared__ __align__(16) ushort_t s_A [128 * 64];
    __shared__ __align__(16) ushort_t s_Bh[128 * 64];
    __shared__ __align__(16) ushort_t s_Bl[128 * 64];
    __shared__ float s_sq[128];

    const int t = threadIdx.x;
    const long mloc = (long)blockIdx.x * 128;
    const int nbase = blockIdx.y * 128;
    const int lane = t & 63, w = t >> 6;
    const int lr = lane & 15, g = lane >> 4;
    const int mrow = (w & 1) * 64, ncol = (w >> 1) * 64;
    const int wu = t & ~63;

    if (t < 128) s_sq[t] = 0.f;

    f32x4 zero4 = {0.f, 0.f, 0.f, 0.f};
    f32x4 acc[4][4];
    #pragma unroll
    for (int mt = 0; mt < 4; ++mt)
        #pragma unroll
        for (int nt = 0; nt < 4; ++nt) acc[mt][nt] = zero4;

    for (int kc = 0; kc < 13; ++kc) {
        const int k0 = kc * 64;
        __syncthreads();
        #pragma unroll
        for (int s = 0; s < 4; ++s) {
            int idx = t + 256 * s;
            int row = idx >> 3, seg = (idx & 7) * 8;
            size_t ldso = (size_t)(wu + 256 * s) * 16;
            glds16(&feat[(mloc + row) * KENC + k0 + seg], (char*)s_A  + ldso);
            glds16(&w_hi[(size_t)(nbase + row) * KENC + k0 + seg], (char*)s_Bh + ldso);
            glds16(&w_lo[(size_t)(nbase + row) * KENC + k0 + seg], (char*)s_Bl + ldso);
        }
        __syncthreads();
        #pragma unroll
        for (int kk = 0; kk < 2; ++kk) {
            const int ko = kk * 32 + g * 8;
            short8 a[4], bh[4], bl[4];
            #pragma unroll
            for (int mt = 0; mt < 4; ++mt)
                a[mt] = *(const short8*)&s_A[(mrow + mt * 16 + lr) * 64 + ko];
            #pragma unroll
            for (int nt = 0; nt < 4; ++nt) {
                bh[nt] = *(const short8*)&s_Bh[(ncol + nt * 16 + lr) * 64 + ko];
                bl[nt] = *(const short8*)&s_Bl[(ncol + nt * 16 + lr) * 64 + ko];
            }
            #pragma unroll
            for (int mt = 0; mt < 4; ++mt)
                #pragma unroll
                for (int nt = 0; nt < 4; ++nt) {
                    acc[mt][nt] = __builtin_amdgcn_mfma_f32_16x16x32_bf16(
                        a[mt], bh[nt], acc[mt][nt], 0, 0, 0);
                    acc[mt][nt] = __builtin_amdgcn_mfma_f32_16x16x32_bf16(
                        a[mt], bl[nt], acc[mt][nt], 0, 0, 0);
                }
        }
    }

    float bias[4];
    #pragma unroll
    for (int nt = 0; nt < 4; ++nt) bias[nt] = encb[nbase + ncol + nt * 16 + lr];

    #pragma unroll
    for (int mt = 0; mt < 4; ++mt) {
        float sqr[4] = {0.f, 0.f, 0.f, 0.f};
        #pragma unroll
        for (int nt = 0; nt < 4; ++nt) {
            #pragma unroll
            for (int r = 0; r < 4; ++r) {
                float v = acc[mt][nt][r] + bias[nt];
                ushort_t hb = f2bf(v);
                float vb = bf2f(hb);
                sqr[r] += vb * vb;
                enc_out[(mbase + mloc + mrow + mt * 16 + g * 4 + r) * 512
                        + nbase + ncol + nt * 16 + lr] = hb;
            }
        }
        #pragma unroll
        for (int r = 0; r < 4; ++r) {
            float vs = sqr[r];
            vs += __shfl_xor(vs, 1);
            vs += __shfl_xor(vs, 2);
            vs += __shfl_xor(vs, 4);
            vs += __shfl_xor(vs, 8);
            if (lr == 0) atomicAdd(&s_sq[mrow + mt * 16 + g * 4 + r], vs);
        }
    }
    __syncthreads();
    if (t < 128) atomicAdd(&sq_out[mbase + mloc + t], s_sq[t]);
}

// ---------------------------------------------------------------------------
// Distance + binning on CLASS-SORTED candidates. Block 256q x 128c.
// Epilogue: per-class masked sums + shfl-reduce; ~1-2 classes per block.
// ---------------------------------------------------------------------------
__global__ __launch_bounds__(256) void dist_kernel(
    const ushort_t* __restrict__ xe,   // [1024][512]
    const ushort_t* __restrict__ ce,   // [100096][512] sorted (pad junk)
    const float*    __restrict__ xsq,  // [1024]
    const float*    __restrict__ csq,  // [100096] sorted
    const int*      __restrict__ scls, // [100096] sorted classes (ascending)
    float*          __restrict__ gbins)// [1024][10]
{
    __shared__ __align__(16) ushort_t s_ce[128 * 64];   // 16384 B
    __shared__ float s_xsq[256];
    __shared__ float s_csq[128];
    __shared__ int   s_y[128];

    const int t = threadIdx.x;
    const int qbase = blockIdx.x * 256;
    const long cbase = (long)blockIdx.y * 128;
    const int lane = t & 63, w = t >> 6;
    const int lr = lane & 15, g = lane >> 4;
    const int wu = t & ~63;

    s_xsq[t] = xsq[qbase + t];
    if (t < 128) {
        long jc = cbase + t;
        s_y[t]   = scls[jc];
        s_csq[t] = (jc < N_CAND) ? csq[jc] : 1e30f;   // pad: exp -> 0
    }

    f32x4 zero4 = {0.f, 0.f, 0.f, 0.f};
    f32x4 acc[4][8];
    #pragma unroll
    for (int mt = 0; mt < 4; ++mt)
        #pragma unroll
        for (int nt = 0; nt < 8; ++nt) acc[mt][nt] = zero4;

    for (int kc = 0; kc < 8; ++kc) {
        const int k0 = kc * 64;
        __syncthreads();
        #pragma unroll
        for (int s = 0; s < 4; ++s) {
            int idx = t + 256 * s;
            int row = idx >> 3, seg = (idx & 7) * 8;
            glds16(&ce[(cbase + row) * 512 + k0 + seg],
                   (char*)s_ce + (size_t)(wu + 256 * s) * 16);
        }
        short8 a[2][4];
        #pragma unroll
        for (int kk = 0; kk < 2; ++kk)
            #pragma unroll
            for (int mt = 0; mt < 4; ++mt)
                a[kk][mt] = *(const short8*)
                    &xe[(size_t)(qbase + w * 64 + mt * 16 + lr) * 512 + k0 + kk * 32 + g * 8];
        __syncthreads();
        #pragma unroll
        for (int kk = 0; kk < 2; ++kk) {
            const int ko = kk * 32 + g * 8;
            short8 b[8];
            #pragma unroll
            for (int nt = 0; nt < 8; ++nt)
                b[nt] = *(const short8*)&s_ce[(nt * 16 + lr) * 64 + ko];
            #pragma unroll
            for (int mt = 0; mt < 4; ++mt)
                #pragma unroll
                for (int nt = 0; nt < 8; ++nt)
                    acc[mt][nt] = __builtin_amdgcn_mfma_f32_16x16x32_bf16(
                        a[kk][mt], b[nt], acc[mt][nt], 0, 0, 0);
        }
    }

    // in-place: acc -> p = exp(-sqrt(max(|x|^2+|c|^2-2dot, eps)))
    float xq[4][4];
    #pragma unroll
    for (int mt = 0; mt < 4; ++mt)
        #pragma unroll
        for (int r = 0; r < 4; ++r)
            xq[mt][r] = s_xsq[w * 64 + mt * 16 + g * 4 + r];

    float cq[8]; int ycls[8];
    #pragma unroll
    for (int nt = 0; nt < 8; ++nt) {
        int c_l = nt * 16 + lr;
        cq[nt]   = s_csq[c_l];
        ycls[nt] = s_y[c_l];
    }
    #pragma unroll
    for (int mt = 0; mt < 4; ++mt)
        #pragma unroll
        for (int nt = 0; nt < 8; ++nt)
            #pragma unroll
            for (int r = 0; r < 4; ++r) {
                float sqv = xq[mt][r] + cq[nt] - 2.f * acc[mt][nt][r];
                acc[mt][nt][r] = __expf(-sqrtf(fmaxf(sqv, 1e-12f)));
            }

    // class range of this block (sorted => contiguous, usually 1, rarely 2)
    long chi = cbase + 127; if (chi > N_CAND - 1) chi = N_CAND - 1;
    const int cls_lo = scls[cbase], cls_hi = scls[chi];

    for (int cls = cls_lo; cls <= cls_hi; ++cls) {
        #pragma unroll
        for (int mt = 0; mt < 4; ++mt) {
            #pragma unroll
            for (int r = 0; r < 4; ++r) {
                float s = 0.f;
                #pragma unroll
                for (int nt = 0; nt < 8; ++nt)
                    s += (ycls[nt] == cls) ? acc[mt][nt][r] : 0.f;
                s += __shfl_xor(s, 1);
                s += __shfl_xor(s, 2);
                s += __shfl_xor(s, 4);
                s += __shfl_xor(s, 8);
                if (lr == 0)
                    atomicAdd(&gbins[(size_t)(qbase + w * 64 + mt * 16 + g * 4 + r) * 10 + cls], s);
            }
        }
    }
}

// ---------------------------------------------------------------------------
__global__ __launch_bounds__(256) void final_kernel(
    const float* __restrict__ gbins, float* __restrict__ out)
{
    int q = blockIdx.x * 256 + threadIdx.x;
    if (q >= N_Q) return;
    float b[10], Z = 0.f;
    #pragma unroll
    for (int c = 0; c < 10; ++c) { b[c] = gbins[q * 10 + c]; Z += b[c]; }
    float inv = 1.f / Z;
    #pragma unroll
    for (int c = 0; c < 10; ++c)
        out[q * 10 + c] = logf(b[c] * inv + 1e-7f);
}

// ---------------------------------------------------------------------------
extern "C" void kernel_launch(void* const* d_in, const int* in_sizes, int n_in,
                              void* d_out, int out_size, void* d_ws, size_t ws_size,
                              hipStream_t stream) {
    const float* x  = (const float*)d_in[0];
    const float* cx = (const float*)d_in[1];
    const int*   cy = (const int*)d_in[2];
    const float* fr = (const float*)d_in[3];
    const float* pw = (const float*)d_in[4];
    const float* pb = (const float*)d_in[5];
    const float* ew = (const float*)d_in[6];
    const float* eb = (const float*)d_in[7];
    float* out = (float*)d_out;

    char* ws = (char*)d_ws;
    ushort_t* ce   = (ushort_t*)(ws);                 // 102,498,304 B
    ushort_t* xe   = (ushort_t*)(ws + 102498304);     //   1,048,576 B
    float*    csq  = (float*)   (ws + 103546880);     //     400,384 B
    float*    xsq  = (float*)   (ws + 103947264);     //       4,096 B
    float*    gbin = (float*)   (ws + 103951360);     //      40,960 B
    int*      hist = (int*)     (ws + 103992320);     //          64 B (zeroed)
    int*      curs = (int*)     (ws + 103992384);     //          64 B
    ushort_t* w_hi = (ushort_t*)(ws + 103992448);     //     851,968 B
    ushort_t* w_lo = (ushort_t*)(ws + 104844416);     //     851,968 B
    ushort_t* fq   = (ushort_t*)(ws + 105696384);     //   1,703,936 B
    int*      perm = (int*)     (ws + 107400320);     //     400,384 B
    int*      scls = (int*)     (ws + 107800704);     //     400,384 B
    ushort_t* fc   = (ushort_t*)(ws + 108201088);     // slab buffer (rest)

    long avail = (long)ws_size - 108201088L;
    long slab = avail / (KENC * 2);
    slab &= ~127L;
    if (slab > N_CPAD) slab = N_CPAD;
    if (slab < 128)    slab = 128;

    // zero csq + xsq + gbin + hist (contiguous region)
    hipMemsetAsync(csq, 0, 445504, stream);
    wsplit_kernel<<<1664, 256, 0, stream>>>(ew, w_hi, w_lo);

    // class counting sort
    hist_kernel<<<391, 256, 0, stream>>>(cy, hist, perm, scls);
    prefix_kernel<<<1, 64, 0, stream>>>(hist, curs);
    scatter_kernel<<<391, 256, 0, stream>>>(cy, curs, perm, scls);

    // queries
    plr_kernel<<<N_Q / 32, 256, 0, stream>>>(x, N_Q, 0, nullptr, fr, pw, pb, fq);
    enc_gemm_kernel<<<dim3(N_Q / 128, 4), 256, 0, stream>>>(
        fq, 0, w_hi, w_lo, eb, xe, xsq);

    // candidates, slab by slab, gathered in sorted order
    for (long sb = 0; sb < N_CPAD; sb += slab) {
        long rows = (N_CPAD - sb < slab) ? (N_CPAD - sb) : slab;
        plr_kernel<<<rows / 32, 256, 0, stream>>>(cx, N_CAND, sb, perm, fr, pw, pb, fc);
        enc_gemm_kernel<<<dim3(rows / 128, 4), 256, 0, stream>>>(
            fc, sb, w_hi, w_lo, eb, ce, csq);
    }

    dist_kernel<<<dim3(4, N_CPAD / 128), 256, 0, stream>>>(xe, ce, xsq, csq, scls, gbin);
    final_kernel<<<4, 256, 0, stream>>>(gbin, out);
}